// Round 6
// baseline (234.289 us; speedup 1.0000x reference)
//
#include <hip/hip_runtime.h>

#define NIN 64
#define NOUT 64
#define NTO 16
#define HH 192
#define WW 192
#define HO 190
#define WO 190
#define NBLK 2304            // 36 groups (9 tiles x 4 batch) x 64 out channels

__global__ __launch_bounds__(256, 4) void scm_kernel(
    const float* __restrict__ x,
    const float* __restrict__ w,
    const float* __restrict__ bias,
    const int* __restrict__ conn_in,
    float* __restrict__ out)
{
    const int tid = threadIdx.x;
    const int tx = tid & 15;        // col group of 4
    const int ty = tid >> 4;        // row group of 4

    // XCD-aware swizzle (bijective, 2304 % 8 == 0), o-minor: the 64 blocks
    // sharing one x-tile region are contiguous on one XCD's L2.
    const int lid = (blockIdx.x & 7) * (NBLK / 8) + (blockIdx.x >> 3);
    const int o   = lid & 63;
    const int g   = lid >> 6;       // 0..35
    const int tile = g % 9;
    const int b    = g / 9;
    const int i0 = (tile / 3) * 64;
    const int j0 = (tile % 3) * 64;

    // Channel-independent per-thread byte offsets for the 6 patch rows.
    // Row clamp <=191: clamped rows feed only outputs >=190 (discarded).
    // float2 col clamp <=190: substituted values feed only discarded taps.
    const int c0 = j0 + tx * 4;                   // 16B-aligned
    const int c2 = (c0 + 4 > 190) ? 190 : c0 + 4; // 8B-aligned
    int off4[6], off2[6];
    #pragma unroll
    for (int r = 0; r < 6; ++r) {
        int gr = i0 + ty * 4 + r; if (gr > 191) gr = 191;
        off4[r] = (gr * WW + c0) * 4;
        off2[r] = (gr * WW + c2) * 4;
    }

    const char* xb = (const char*)x + (size_t)b * NIN * HH * WW * 4;
    const int kbase = o * NTO;

    float acc[4][4];
    #pragma unroll
    for (int i = 0; i < 4; ++i)
        #pragma unroll
        for (int p = 0; p < 4; ++p) acc[i][p] = 0.f;

    // Double register buffers (STATIC names only — no runtime indexing).
    float4 A4[6]; float2 A2[6]; float Aw[9];
    float4 B4[6]; float2 B2[6]; float Bw[9];

#define LOADP(D4, D2, DW, t) do {                                              \
        const int _ci = __builtin_amdgcn_readfirstlane(conn_in[kbase + (t)]);  \
        const char* _xc = xb + (size_t)_ci * (HH * WW * 4);                    \
        _Pragma("unroll")                                                      \
        for (int _r = 0; _r < 6; ++_r) {                                       \
            D4[_r] = *(const float4*)(_xc + off4[_r]);                         \
            D2[_r] = *(const float2*)(_xc + off2[_r]);                         \
        }                                                                      \
        const float* _wp = w + (size_t)(kbase + (t)) * 9;                      \
        _Pragma("unroll")                                                      \
        for (int _q = 0; _q < 9; ++_q) DW[_q] = _wp[_q];                       \
    } while (0)

#define COMPUTE(S4, S2, SW) do {                                               \
        _Pragma("unroll")                                                      \
        for (int _r = 0; _r < 6; ++_r) {                                       \
            const float _rv[6] = {S4[_r].x, S4[_r].y, S4[_r].z, S4[_r].w,      \
                                  S2[_r].x, S2[_r].y};                         \
            _Pragma("unroll")                                                  \
            for (int _i = 0; _i < 4; ++_i) {                                   \
                const int _kh = _r - _i;                                       \
                if (_kh >= 0 && _kh < 3) {                                     \
                    _Pragma("unroll")                                          \
                    for (int _kw = 0; _kw < 3; ++_kw) {                        \
                        const float _wk = SW[_kh * 3 + _kw];                   \
                        _Pragma("unroll")                                      \
                        for (int _p = 0; _p < 4; ++_p)                         \
                            acc[_i][_p] = fmaf(_wk, _rv[_p + _kw], acc[_i][_p]); \
                    }                                                          \
                }                                                              \
            }                                                                  \
        }                                                                      \
    } while (0)

    LOADP(A4, A2, Aw, 0);
    #pragma unroll 1
    for (int tt = 0; tt < NTO / 2; ++tt) {
        LOADP(B4, B2, Bw, 2 * tt + 1);       // issue next-channel loads (no deps on A)
        COMPUTE(A4, A2, Aw);                 // consume A while B's loads fly
        if (tt < NTO / 2 - 1)
            LOADP(A4, A2, Aw, 2 * tt + 2);
        COMPUTE(B4, B2, Bw);
    }
#undef LOADP
#undef COMPUTE

    const float bv = bias[o];
    float* outp = out + (size_t)(b * NOUT + o) * (HO * WO);
    #pragma unroll
    for (int i = 0; i < 4; ++i) {
        const int gi = i0 + ty * 4 + i;
        if (gi < HO) {
            const int gj = j0 + tx * 4;
            float* row = outp + (size_t)gi * WO + gj;
            if (gj + 3 < WO) {
                *(float2*)(row)     = make_float2(acc[i][0] + bv, acc[i][1] + bv);
                *(float2*)(row + 2) = make_float2(acc[i][2] + bv, acc[i][3] + bv);
            } else {
                #pragma unroll
                for (int p = 0; p < 4; ++p)
                    if (gj + p < WO) row[p] = acc[i][p] + bv;
            }
        }
    }
}

extern "C" void kernel_launch(void* const* d_in, const int* in_sizes, int n_in,
                              void* d_out, int out_size, void* d_ws, size_t ws_size,
                              hipStream_t stream) {
    const float* x       = (const float*)d_in[0];
    const float* weight  = (const float*)d_in[1];
    const float* bias    = (const float*)d_in[2];
    const int*   conn_in = (const int*)d_in[3];
    // d_in[4] = conn_out (implicit: k -> k/16)

    dim3 grid(NBLK);
    dim3 block(256);
    scm_kernel<<<grid, block, 0, stream>>>(x, weight, bias, conn_in, (float*)d_out);
}

// Round 7
// 233.983 us; speedup vs baseline: 1.0013x; 1.0013x over previous
//
#include <hip/hip_runtime.h>

#define NIN 64
#define NOUT 64
#define NTO 16
#define HH 192
#define WW 192
#define HO 190
#define WO 190
#define NBLK 2304            // 36 groups (9 tiles x 4 batch) x 64 out channels

__global__ __launch_bounds__(256, 4) void scm_kernel(
    const float* __restrict__ x,
    const float* __restrict__ w,
    const float* __restrict__ bias,
    const int* __restrict__ conn_in,
    float* __restrict__ out)
{
    const int tid = threadIdx.x;
    const int tx = tid & 15;        // col group of 4
    const int ty = tid >> 4;        // row group of 4

    // XCD-aware swizzle (bijective, 2304 % 8 == 0), o-minor: the 64 blocks
    // sharing one x-tile region are contiguous on one XCD's L2.
    const int lid = (blockIdx.x & 7) * (NBLK / 8) + (blockIdx.x >> 3);
    const int o   = lid & 63;
    const int g   = lid >> 6;       // 0..35
    const int tile = g % 9;
    const int b    = g / 9;
    const int i0 = (tile / 3) * 64;
    const int j0 = (tile % 3) * 64;

    // Channel-independent per-thread byte offsets for the 6 patch rows.
    // Row clamp <=191: clamped rows feed only outputs >=190 (discarded).
    // float2 col clamp <=190: substituted values feed only discarded taps.
    const int c0 = j0 + tx * 4;                   // 16B-aligned
    const int c2 = (c0 + 4 > 190) ? 190 : c0 + 4; // 8B-aligned
    int off4[6], off2[6];
    #pragma unroll
    for (int r = 0; r < 6; ++r) {
        int gr = i0 + ty * 4 + r; if (gr > 191) gr = 191;
        off4[r] = (gr * WW + c0) * 4;
        off2[r] = (gr * WW + c2) * 4;
    }

    const char* xb = (const char*)x + (size_t)b * NIN * HH * WW * 4;
    const int kbase = o * NTO;

    float acc[4][4];
    #pragma unroll
    for (int i = 0; i < 4; ++i)
        #pragma unroll
        for (int p = 0; p < 4; ++p) acc[i][p] = 0.f;

    // Double register buffers (STATIC names only — no runtime indexing).
    float4 A4[6]; float2 A2[6]; float Aw[9];
    float4 B4[6]; float2 B2[6]; float Bw[9];

#define LOADP(D4, D2, DW, t) do {                                              \
        const int _ci = __builtin_amdgcn_readfirstlane(conn_in[kbase + (t)]);  \
        const char* _xc = xb + (size_t)_ci * (HH * WW * 4);                    \
        _Pragma("unroll")                                                      \
        for (int _r = 0; _r < 6; ++_r) {                                       \
            D4[_r] = *(const float4*)(_xc + off4[_r]);                         \
            D2[_r] = *(const float2*)(_xc + off2[_r]);                         \
        }                                                                      \
        const float* _wp = w + (size_t)(kbase + (t)) * 9;                      \
        _Pragma("unroll")                                                      \
        for (int _q = 0; _q < 9; ++_q) DW[_q] = _wp[_q];                       \
    } while (0)

#define COMPUTE(S4, S2, SW) do {                                               \
        _Pragma("unroll")                                                      \
        for (int _r = 0; _r < 6; ++_r) {                                       \
            const float _rv[6] = {S4[_r].x, S4[_r].y, S4[_r].z, S4[_r].w,      \
                                  S2[_r].x, S2[_r].y};                         \
            _Pragma("unroll")                                                  \
            for (int _i = 0; _i < 4; ++_i) {                                   \
                const int _kh = _r - _i;                                       \
                if (_kh >= 0 && _kh < 3) {                                     \
                    _Pragma("unroll")                                          \
                    for (int _kw = 0; _kw < 3; ++_kw) {                        \
                        const float _wk = SW[_kh * 3 + _kw];                   \
                        _Pragma("unroll")                                      \
                        for (int _p = 0; _p < 4; ++_p)                         \
                            acc[_i][_p] = fmaf(_wk, _rv[_p + _kw], acc[_i][_p]); \
                    }                                                          \
                }                                                              \
            }                                                                  \
        }                                                                      \
    } while (0)

    LOADP(A4, A2, Aw, 0);
    #pragma unroll 1
    for (int tt = 0; tt < NTO / 2; ++tt) {
        LOADP(B4, B2, Bw, 2 * tt + 1);       // issue next-channel loads (no deps on A)
        COMPUTE(A4, A2, Aw);                 // consume A while B's loads fly
        if (tt < NTO / 2 - 1)
            LOADP(A4, A2, Aw, 2 * tt + 2);
        COMPUTE(B4, B2, Bw);
    }
#undef LOADP
#undef COMPUTE

    const float bv = bias[o];
    float* outp = out + (size_t)(b * NOUT + o) * (HO * WO);
    #pragma unroll
    for (int i = 0; i < 4; ++i) {
        const int gi = i0 + ty * 4 + i;
        if (gi < HO) {
            const int gj = j0 + tx * 4;
            float* row = outp + (size_t)gi * WO + gj;
            if (gj + 3 < WO) {
                *(float2*)(row)     = make_float2(acc[i][0] + bv, acc[i][1] + bv);
                *(float2*)(row + 2) = make_float2(acc[i][2] + bv, acc[i][3] + bv);
            } else {
                #pragma unroll
                for (int p = 0; p < 4; ++p)
                    if (gj + p < WO) row[p] = acc[i][p] + bv;
            }
        }
    }
}

extern "C" void kernel_launch(void* const* d_in, const int* in_sizes, int n_in,
                              void* d_out, int out_size, void* d_ws, size_t ws_size,
                              hipStream_t stream) {
    const float* x       = (const float*)d_in[0];
    const float* weight  = (const float*)d_in[1];
    const float* bias    = (const float*)d_in[2];
    const int*   conn_in = (const int*)d_in[3];
    // d_in[4] = conn_out (implicit: k -> k/16)

    dim3 grid(NBLK);
    dim3 block(256);
    scm_kernel<<<grid, block, 0, stream>>>(x, weight, bias, conn_in, (float*)d_out);
}

// Round 8
// 69.021 us; speedup vs baseline: 3.3945x; 3.3900x over previous
//
#include <hip/hip_runtime.h>

#define NIN 64
#define NOUT 64
#define NTO 16
#define HH 192
#define WW 192
#define HO 190
#define WO 190
#define WBUF 5120            // per-wave per-channel buffer: 288 main units + 18 halo + 14 pad = 320*16B
#define NBLK 2304            // 36 groups (9 tiles x 4 batch) x 64 out channels

typedef const __attribute__((address_space(1))) void gv_t;
typedef __attribute__((address_space(3))) void lv_t;

__global__ __launch_bounds__(256, 4) void scm_kernel(
    const float* __restrict__ x,
    const float* __restrict__ w,
    const float* __restrict__ bias,
    const int* __restrict__ conn_in,
    float* __restrict__ out)
{
    __shared__ char smem[4 * 2 * WBUF];   // 40960 B: 4 waves x double buffer

    const int tid  = threadIdx.x;
    const int lane = tid & 63;
    const int tx   = tid & 15;       // col group of 4
    const int ty   = tid >> 4;       // row group of 4 (block-wide)
    const int wv   = ty >> 2;        // wave id 0..3 (rows 16*wv .. +15)
    const int lty  = ty & 3;         // row group within wave

    // XCD-aware swizzle (bijective, 2304 % 8 == 0), o-minor for L2 gather reuse.
    const int lid = (blockIdx.x & 7) * (NBLK / 8) + (blockIdx.x >> 3);
    const int o   = lid & 63;
    const int g   = lid >> 6;        // 0..35
    const int tile = g % 9;
    const int b    = g / 9;
    const int i0 = (tile / 3) * 64;
    const int j0 = (tile % 3) * 64;

    // ---- Wave-private LDS layout (per buffer, 5120 B):
    //   bytes [0..4607]    main[18 rows][16 units of 16B]  (256 B row stride)
    //   bytes [4608..4895] halo[18 rows][16B]  = global cols j0+64..67
    //   bytes [4896..5119] pad (written, never read)
    // Staged by 5 global_load_lds rounds of 64 lanes; physical unit u = s*64+lane.
    // Clamped slots feed only outputs >= row/col 190, which are discarded.
    int goff[5];
    #pragma unroll
    for (int s = 0; s < 5; ++s) {
        int u = s * 64 + lane;
        int gr, gc;
        if (u < 288)      { int row = u >> 4; gr = i0 + 16 * wv + row; gc = j0 + 4 * (u & 15); }
        else if (u < 306) { int row = u - 288; gr = i0 + 16 * wv + row;
                            gc = j0 + 64; if (gc > 188) gc = 188; }
        else              { gr = 191; gc = 0; }
        if (gr > 191) gr = 191;
        goff[s] = (gr * WW + gc) * 4;
    }

    // Read offsets within the wave buffer (channel-independent):
    //   A = float4 cols tx*4..+3   at main[lr][tx]
    //   B = float2 cols tx*4+4,+5  = first 8B of main[lr][tx+1], or halo[lr] for tx=15
    int offA[6], offB[6];
    #pragma unroll
    for (int r = 0; r < 6; ++r) {
        int lr = lty * 4 + r;
        offA[r] = lr * 256 + tx * 16;
        offB[r] = (tx < 15) ? (lr * 256 + (tx + 1) * 16) : (4608 + lr * 16);
    }

    char* wbase = smem + wv * (2 * WBUF);
    const char* xb = (const char*)x + (size_t)b * NIN * HH * WW * 4;
    const int kbase = o * NTO;

#define STAGE(ci, buf) do {                                                     \
        const char* _src = xb + (size_t)(ci) * (HH * WW * 4);                   \
        char* _lb = wbase + (buf) * WBUF;                                       \
        _Pragma("unroll")                                                       \
        for (int _s = 0; _s < 5; ++_s)                                          \
            __builtin_amdgcn_global_load_lds((gv_t*)(_src + goff[_s]),          \
                                             (lv_t*)(_lb + _s * 1024),          \
                                             16, 0, 0);                         \
    } while (0)

    float acc[4][4];
    #pragma unroll
    for (int i = 0; i < 4; ++i)
        #pragma unroll
        for (int p = 0; p < 4; ++p) acc[i][p] = 0.f;

    // prologue: stage channel 0 into buffer 0
    {
        const int c0 = __builtin_amdgcn_readfirstlane(conn_in[kbase]);
        STAGE(c0, 0);
    }

    #pragma unroll 1
    for (int t = 0; t < NTO; ++t) {
        const int cur = t & 1;

        // Before re-staging buffer cur^1: our reads of it (iter t-1) must have
        // retired. Wave-local, essentially free (values were consumed by FMAs).
        asm volatile("s_waitcnt lgkmcnt(0)" ::: "memory");
        __builtin_amdgcn_sched_barrier(0);
        if (t < NTO - 1) {
            const int cn = __builtin_amdgcn_readfirstlane(conn_in[kbase + t + 1]);
            STAGE(cn, cur ^ 1);
        }

        float wv9[9];
        #pragma unroll
        for (int q = 0; q < 9; ++q) wv9[q] = w[(kbase + t) * 9 + q];

        // Wait for THIS channel's 5 DMA loads; keep next channel's 5 in flight.
        if (t < NTO - 1) asm volatile("s_waitcnt vmcnt(5)" ::: "memory");
        else             asm volatile("s_waitcnt vmcnt(0)" ::: "memory");
        __builtin_amdgcn_sched_barrier(0);

        const char* rb = wbase + cur * WBUF;
        #pragma unroll
        for (int r = 0; r < 6; ++r) {
            const float4 v4 = *(const float4*)(rb + offA[r]);
            const float2 v2 = *(const float2*)(rb + offB[r]);
            const float rowv[6] = {v4.x, v4.y, v4.z, v4.w, v2.x, v2.y};
            #pragma unroll
            for (int i = 0; i < 4; ++i) {
                const int kh = r - i;
                if (kh >= 0 && kh < 3) {
                    #pragma unroll
                    for (int kw = 0; kw < 3; ++kw) {
                        const float wk = wv9[kh * 3 + kw];
                        #pragma unroll
                        for (int p = 0; p < 4; ++p)
                            acc[i][p] = fmaf(wk, rowv[p + kw], acc[i][p]);
                    }
                }
            }
        }
    }
#undef STAGE

    const float bv = bias[o];
    float* outp = out + (size_t)(b * NOUT + o) * (HO * WO);
    #pragma unroll
    for (int i = 0; i < 4; ++i) {
        const int gi = i0 + ty * 4 + i;
        if (gi < HO) {
            const int gj = j0 + tx * 4;
            float* row = outp + (size_t)gi * WO + gj;
            if (gj + 3 < WO) {
                *(float2*)(row)     = make_float2(acc[i][0] + bv, acc[i][1] + bv);
                *(float2*)(row + 2) = make_float2(acc[i][2] + bv, acc[i][3] + bv);
            } else {
                #pragma unroll
                for (int p = 0; p < 4; ++p)
                    if (gj + p < WO) row[p] = acc[i][p] + bv;
            }
        }
    }
}

extern "C" void kernel_launch(void* const* d_in, const int* in_sizes, int n_in,
                              void* d_out, int out_size, void* d_ws, size_t ws_size,
                              hipStream_t stream) {
    const float* x       = (const float*)d_in[0];
    const float* weight  = (const float*)d_in[1];
    const float* bias    = (const float*)d_in[2];
    const int*   conn_in = (const int*)d_in[3];
    // d_in[4] = conn_out (implicit: k -> k/16)

    dim3 grid(NBLK);
    dim3 block(256);
    scm_kernel<<<grid, block, 0, stream>>>(x, weight, bias, conn_in, (float*)d_out);
}